// Round 2
// baseline (179.433 us; speedup 1.0000x reference)
//
#include <hip/hip_runtime.h>
#include <hip/hip_bf16.h>
#include <stdint.h>

// Problem constants
#define NC 512     // NUM_CLASSES
#define FD 1024    // FEAT_DIM
#define NB 64      // BATCH
#define SMOOTH_ 0.01f

typedef __bf16 bf16x8 __attribute__((ext_vector_type(8)));
typedef float f32x4 __attribute__((ext_vector_type(4)));
typedef unsigned short u16x8 __attribute__((ext_vector_type(8)));

__device__ __forceinline__ unsigned short f2bf(float f) {
    __hip_bfloat16 h = __float2bfloat16(f);
    return __builtin_bit_cast(unsigned short, h);
}
__device__ __forceinline__ float bf2f(unsigned short u) {
    unsigned int v = (unsigned int)u << 16;
    return __builtin_bit_cast(float, v);
}

__device__ __forceinline__ void gload_lds16(const void* g, void* l) {
    __builtin_amdgcn_global_load_lds(
        (const __attribute__((address_space(1))) void*)(uintptr_t)g,
        (__attribute__((address_space(3))) void*)(uint32_t)(uintptr_t)l,
        16, 0, 0);
}

// ---------------------------------------------------------------------------
// K1: build edge weights ew[512][512], store as bf16 bits. (unchanged, verified)
// ---------------------------------------------------------------------------
__global__ __launch_bounds__(256) void build_ew(
    const float* __restrict__ co, const float* __restrict__ counts,
    const float* __restrict__ emb, unsigned short* __restrict__ ew) {
    __shared__ float s_counts[NC];
    __shared__ float s_nemb[NC * 4];
    __shared__ float s_redA[4], s_redM[4], s_redS[4];
    const int i = blockIdx.x;
    const int t = threadIdx.x;
    const int lane = t & 63, wv = t >> 6;

    float c0 = counts[t], c1 = counts[t + 256];
    s_counts[t] = c0;
    s_counts[t + 256] = c1;
    for (int r = t; r < NC; r += 256) {
        float e0 = emb[r * 4 + 0], e1 = emb[r * 4 + 1];
        float e2 = emb[r * 4 + 2], e3 = emb[r * 4 + 3];
        float inv = 1.0f / sqrtf(e0 * e0 + e1 * e1 + e2 * e2 + e3 * e3);
        s_nemb[r * 4 + 0] = e0 * inv;
        s_nemb[r * 4 + 1] = e1 * inv;
        s_nemb[r * 4 + 2] = e2 * inv;
        s_nemb[r * 4 + 3] = e3 * inv;
    }
    float p = c0 + c1;
#pragma unroll
    for (int o = 32; o; o >>= 1) p += __shfl_down(p, o);
    if (lane == 0) s_redA[wv] = p;
    __syncthreads();
    const float avg = (s_redA[0] + s_redA[1] + s_redA[2] + s_redA[3]) * (1.0f / 512.0f);

    const float ci = s_counts[i];
    const float ni0 = s_nemb[i * 4 + 0], ni1 = s_nemb[i * 4 + 1];
    const float ni2 = s_nemb[i * 4 + 2], ni3 = s_nemb[i * 4 + 3];

    float v[2];
#pragma unroll
    for (int u = 0; u < 2; ++u) {
        const int j = t + u * 256;
        const float c = co[i * NC + j];
        const float cj = s_counts[j];
        const float nco = (c + SMOOTH_) / sqrtf((ci + SMOOTH_) * (cj + SMOOTH_));
        const float sim = ni0 * s_nemb[j * 4 + 0] + ni1 * s_nemb[j * 4 + 1] +
                          ni2 * s_nemb[j * 4 + 2] + ni3 * s_nemb[j * 4 + 3];
        const float aff = sim / (1.0f + expf(-(sim - 0.5f) * 10.0f));
        const float mn = fminf(ci, cj), mx = fmaxf(ci, cj);
        const float bal = (mn > SMOOTH_ && mx > SMOOTH_)
                              ? log1pf(mx / avg) * (mn / mx)
                              : SMOOTH_;
        const float conf = 2.0f / (1.0f + expf(-c * 0.2f)) - 1.0f;
        const float e = (j == i) ? 0.0f : nco * aff * bal * conf;
        v[u] = e * 5.0f;
    }
    float m = fmaxf(v[0], v[1]);
#pragma unroll
    for (int o = 32; o; o >>= 1) m = fmaxf(m, __shfl_down(m, o));
    if (lane == 0) s_redM[wv] = m;
    __syncthreads();
    const float rowmax = fmaxf(fmaxf(s_redM[0], s_redM[1]), fmaxf(s_redM[2], s_redM[3]));
    const float e0 = expf(v[0] - rowmax), e1 = expf(v[1] - rowmax);
    float s = e0 + e1;
#pragma unroll
    for (int o = 32; o; o >>= 1) s += __shfl_down(s, o);
    if (lane == 0) s_redS[wv] = s;
    __syncthreads();
    const float scale = 0.9f / (s_redS[0] + s_redS[1] + s_redS[2] + s_redS[3]);
    const float w0 = e0 * scale + ((t == i) ? 0.1f : 0.0f);
    const float w1 = e1 * scale + ((t + 256 == i) ? 0.1f : 0.0f);
    ew[i * NC + t] = f2bf(w0);
    ew[i * NC + t + 256] = f2bf(w1);
}

// ---------------------------------------------------------------------------
// K2: cast x[b,j,d] (f32) -> xT[b,d,j] (bf16 bits). (unchanged, verified)
// ---------------------------------------------------------------------------
__global__ __launch_bounds__(256) void cast_transpose(
    const float* __restrict__ x, unsigned short* __restrict__ xT) {
    __shared__ unsigned short sm[64][65];
    const int b = blockIdx.z;
    const int d0 = blockIdx.x * 64, j0 = blockIdx.y * 64;
    const int t = threadIdx.x;
    {
        const int jr = t >> 4, dc = (t & 15) * 4;
        const float* src = x + ((size_t)(b * NC + j0 + jr)) * FD + d0 + dc;
#pragma unroll
        for (int p = 0; p < 4; ++p) {
            float4 v = *reinterpret_cast<const float4*>(src + (size_t)p * 16 * FD);
            sm[jr + p * 16][dc + 0] = f2bf(v.x);
            sm[jr + p * 16][dc + 1] = f2bf(v.y);
            sm[jr + p * 16][dc + 2] = f2bf(v.z);
            sm[jr + p * 16][dc + 3] = f2bf(v.w);
        }
    }
    __syncthreads();
    {
        const int dl = t >> 4, jc = (t & 15) * 4;
        unsigned short* dst = xT + ((size_t)(b * FD + d0 + dl)) * NC + j0 + jc;
#pragma unroll
        for (int p = 0; p < 4; ++p) {
            const int d = dl + p * 16;
            ushort4 v;
            v.x = sm[jc + 0][d];
            v.y = sm[jc + 1][d];
            v.z = sm[jc + 2][d];
            v.w = sm[jc + 3][d];
            *reinterpret_cast<ushort4*>(dst + (size_t)p * 16 * NC) = v;
        }
    }
}

// ---------------------------------------------------------------------------
// K3 (fused): per block = (64-row i-panel, batch b), full N=1024.
// Phase 1: 8 n-chunks x (K=512) MFMA; x_t stored bf16-packed into the first
//          2048 B of each output row's 4 KB slot in d_out (block-local).
// Phase 2: per row: dot(x, x_t) -> sigmoid gate -> blend -> final f32 row
//          overwrites the slot. Per-lane RAW is safe: every stored value
//          data-depends (via the shuffle-reduced dot) on all lanes' xt loads.
// Waves split columns in phase 1 (w*32..w*32+32 of each 128-chunk), rows in
// phase 2 (w*16..w*16+16). Cross-wave visibility: __syncthreads vmcnt drain,
// readback lines never resident in L1.
// Grid: 512 blocks, 1-D, swizzled so the 8 i-panels of a batch land on one
// XCD (bid%8 = b%8) adjacently -> xT[b] (1 MB) fetched ~once from HBM.
// ---------------------------------------------------------------------------
__global__ __launch_bounds__(256) void gemm_gate(
    const unsigned short* __restrict__ ew, const unsigned short* __restrict__ xT,
    const float* __restrict__ x, float* __restrict__ out) {
    __shared__ __align__(16) unsigned short smA[2][64 * 32];   // 2 x 4 KB
    __shared__ __align__(16) unsigned short smB[2][128 * 32];  // 2 x 8 KB
    const int t = threadIdx.x;
    const int lane = t & 63, w = t >> 6;
    const int bid = blockIdx.x;
    const int slot = bid & 7, idx = bid >> 3;
    const int i_t = idx & 7, bq = idx >> 3;
    const int b = slot + bq * 8;   // XCD = b % 8; i-panels of same b adjacent
    const int i0 = i_t * 64;

    const int arow = t >> 2, acol = (t & 3) * 8;
    const unsigned short* gA = ew + (size_t)(i0 + arow) * NC + acol;
    const unsigned short* gB = xT + ((size_t)b * FD + arow) * NC + acol;

    const int lr = lane & 15, kidx = lane >> 4;

    auto STAGE = [&](int s, int p) {
        const int c = s >> 4, k0 = (s & 15) * 32;
        gload_lds16(gA + k0, &smA[p][t * 8]);
        const unsigned short* gb = gB + (size_t)c * 128 * NC + k0;
        gload_lds16(gb, &smB[p][t * 8]);
        gload_lds16(gb + (size_t)64 * NC, &smB[p][2048 + t * 8]);
    };

    f32x4 acc[4][2];
    unsigned short* xts = (unsigned short*)out;

    STAGE(0, 0);
    int p = 0;
    for (int c = 0; c < 8; ++c) {
#pragma unroll
        for (int mi = 0; mi < 4; ++mi)
#pragma unroll
            for (int ni = 0; ni < 2; ++ni) acc[mi][ni] = (f32x4){0.f, 0.f, 0.f, 0.f};
        for (int kt = 0; kt < 16; ++kt) {
            const int s = c * 16 + kt;
            __syncthreads();  // drains vmcnt: buf p loads complete; prior reads done
            if (s + 1 < 128) STAGE(s + 1, p ^ 1);
            const bf16x8* A8 = reinterpret_cast<const bf16x8*>(smA[p]);
            const bf16x8* B8 = reinterpret_cast<const bf16x8*>(smB[p]);
            bf16x8 aF[4], bF[2];
#pragma unroll
            for (int mi = 0; mi < 4; ++mi) aF[mi] = A8[(mi * 16 + lr) * 4 + kidx];
#pragma unroll
            for (int ni = 0; ni < 2; ++ni)
                bF[ni] = B8[(w * 32 + ni * 16 + lr) * 4 + kidx];
#pragma unroll
            for (int mi = 0; mi < 4; ++mi)
#pragma unroll
                for (int ni = 0; ni < 2; ++ni)
                    acc[mi][ni] = __builtin_amdgcn_mfma_f32_16x16x32_bf16(
                        aF[mi], bF[ni], acc[mi][ni], 0, 0, 0);
            p ^= 1;
        }
        // chunk epilogue: xt bf16 into first 2048 B of each row's 4 KB slot
#pragma unroll
        for (int mi = 0; mi < 4; ++mi)
#pragma unroll
            for (int r = 0; r < 4; ++r) {
                const size_t R = (size_t)b * NC + i0 + mi * 16 + (lane >> 4) * 4 + r;
#pragma unroll
                for (int ni = 0; ni < 2; ++ni) {
                    const int d = c * 128 + w * 32 + ni * 16 + lr;
                    xts[R * 2048 + d] = f2bf(acc[mi][ni][r]);
                }
            }
    }
    __syncthreads();  // all waves' xt stores complete (vmcnt drain) before readback

    // Phase 2: wave w owns rows [w*16, w*16+16); lane owns d in [lane*16, lane*16+16)
    for (int rr = 0; rr < 16; ++rr) {
        const size_t R = (size_t)b * NC + i0 + w * 16 + rr;
        const u16x8* xtp =
            reinterpret_cast<const u16x8*>(xts + R * 2048 + lane * 16);
        const u16x8 u0 = xtp[0], u1 = xtp[1];
        float tv[16];
#pragma unroll
        for (int e = 0; e < 8; ++e) {
            tv[e] = bf2f(u0[e]);
            tv[8 + e] = bf2f(u1[e]);
        }
        const float* xr = x + R * 1024 + lane * 16;
        float xv[16];
#pragma unroll
        for (int q = 0; q < 4; ++q) {
            float4 v = *reinterpret_cast<const float4*>(xr + q * 4);
            xv[q * 4 + 0] = v.x;
            xv[q * 4 + 1] = v.y;
            xv[q * 4 + 2] = v.z;
            xv[q * 4 + 3] = v.w;
        }
        float pd = 0.f;
#pragma unroll
        for (int e = 0; e < 16; ++e) pd += xv[e] * tv[e];
#pragma unroll
        for (int o = 32; o; o >>= 1) pd += __shfl_xor(pd, o);
        const float g = 1.0f / (1.0f + expf(-pd * 0.03125f));
        float* orow = out + R * 1024 + lane * 16;
#pragma unroll
        for (int q = 0; q < 4; ++q) {
            float4 ov;
            ov.x = xv[q * 4 + 0] * (1.f - g) + tv[q * 4 + 0] * g;
            ov.y = xv[q * 4 + 1] * (1.f - g) + tv[q * 4 + 1] * g;
            ov.z = xv[q * 4 + 2] * (1.f - g) + tv[q * 4 + 2] * g;
            ov.w = xv[q * 4 + 3] * (1.f - g) + tv[q * 4 + 3] * g;
            *reinterpret_cast<float4*>(orow + q * 4) = ov;
        }
    }
}

extern "C" void kernel_launch(void* const* d_in, const int* in_sizes, int n_in,
                              void* d_out, int out_size, void* d_ws, size_t ws_size,
                              hipStream_t stream) {
    const float* x = (const float*)d_in[0];
    const float* co = (const float*)d_in[1];
    const float* counts = (const float*)d_in[2];
    const float* emb = (const float*)d_in[3];
    float* out = (float*)d_out;

    unsigned short* ew = (unsigned short*)d_ws;                        // 512 KB
    unsigned short* xT = (unsigned short*)((char*)d_ws + (1u << 20));  // 64 MiB

    build_ew<<<NC, 256, 0, stream>>>(co, counts, emb, ew);
    cast_transpose<<<dim3(FD / 64, NC / 64, NB), 256, 0, stream>>>(x, xT);
    gemm_gate<<<512, 256, 0, stream>>>(ew, xT, x, out);
}

// Round 5
// 131.963 us; speedup vs baseline: 1.3597x; 1.3597x over previous
//
#include <hip/hip_runtime.h>
#include <hip/hip_bf16.h>
#include <stdint.h>

// Problem constants
#define NC 512     // NUM_CLASSES
#define FD 1024    // FEAT_DIM
#define NB 64      // BATCH
#define SMOOTH_ 0.01f
#define ST 132     // smT row stride in u16: 264 B rows -> ushort4 stores 8B-aligned;
                   // reads & writes <=2-way bank aliasing (free, m136)

typedef __bf16 bf16x8 __attribute__((ext_vector_type(8)));
typedef float f32x4 __attribute__((ext_vector_type(4)));
typedef unsigned int u32x4 __attribute__((ext_vector_type(4)));

__device__ __forceinline__ unsigned short f2bf(float f) {
    __hip_bfloat16 h = __float2bfloat16(f);
    return __builtin_bit_cast(unsigned short, h);
}
__device__ __forceinline__ float bf2f(unsigned short u) {
    unsigned int v = (unsigned int)u << 16;
    return __builtin_bit_cast(float, v);
}

__device__ __forceinline__ void gload_lds16(const void* g, void* l) {
    __builtin_amdgcn_global_load_lds(
        (const __attribute__((address_space(1))) void*)(uintptr_t)g,
        (__attribute__((address_space(3))) void*)(uint32_t)(uintptr_t)l,
        16, 0, 0);
}

// ---------------------------------------------------------------------------
// K1: build edge weights ew[512][512], store as bf16 bits. (unchanged, verified)
// ---------------------------------------------------------------------------
__global__ __launch_bounds__(256) void build_ew(
    const float* __restrict__ co, const float* __restrict__ counts,
    const float* __restrict__ emb, unsigned short* __restrict__ ew) {
    __shared__ float s_counts[NC];
    __shared__ float s_nemb[NC * 4];
    __shared__ float s_redA[4], s_redM[4], s_redS[4];
    const int i = blockIdx.x;
    const int t = threadIdx.x;
    const int lane = t & 63, wv = t >> 6;

    float c0 = counts[t], c1 = counts[t + 256];
    s_counts[t] = c0;
    s_counts[t + 256] = c1;
    for (int r = t; r < NC; r += 256) {
        float e0 = emb[r * 4 + 0], e1 = emb[r * 4 + 1];
        float e2 = emb[r * 4 + 2], e3 = emb[r * 4 + 3];
        float inv = 1.0f / sqrtf(e0 * e0 + e1 * e1 + e2 * e2 + e3 * e3);
        s_nemb[r * 4 + 0] = e0 * inv;
        s_nemb[r * 4 + 1] = e1 * inv;
        s_nemb[r * 4 + 2] = e2 * inv;
        s_nemb[r * 4 + 3] = e3 * inv;
    }
    float p = c0 + c1;
#pragma unroll
    for (int o = 32; o; o >>= 1) p += __shfl_down(p, o);
    if (lane == 0) s_redA[wv] = p;
    __syncthreads();
    const float avg = (s_redA[0] + s_redA[1] + s_redA[2] + s_redA[3]) * (1.0f / 512.0f);

    const float ci = s_counts[i];
    const float ni0 = s_nemb[i * 4 + 0], ni1 = s_nemb[i * 4 + 1];
    const float ni2 = s_nemb[i * 4 + 2], ni3 = s_nemb[i * 4 + 3];

    float v[2];
#pragma unroll
    for (int u = 0; u < 2; ++u) {
        const int j = t + u * 256;
        const float c = co[i * NC + j];
        const float cj = s_counts[j];
        const float nco = (c + SMOOTH_) / sqrtf((ci + SMOOTH_) * (cj + SMOOTH_));
        const float sim = ni0 * s_nemb[j * 4 + 0] + ni1 * s_nemb[j * 4 + 1] +
                          ni2 * s_nemb[j * 4 + 2] + ni3 * s_nemb[j * 4 + 3];
        const float aff = sim / (1.0f + expf(-(sim - 0.5f) * 10.0f));
        const float mn = fminf(ci, cj), mx = fmaxf(ci, cj);
        const float bal = (mn > SMOOTH_ && mx > SMOOTH_)
                              ? log1pf(mx / avg) * (mn / mx)
                              : SMOOTH_;
        const float conf = 2.0f / (1.0f + expf(-c * 0.2f)) - 1.0f;
        const float e = (j == i) ? 0.0f : nco * aff * bal * conf;
        v[u] = e * 5.0f;
    }
    float m = fmaxf(v[0], v[1]);
#pragma unroll
    for (int o = 32; o; o >>= 1) m = fmaxf(m, __shfl_down(m, o));
    if (lane == 0) s_redM[wv] = m;
    __syncthreads();
    const float rowmax = fmaxf(fmaxf(s_redM[0], s_redM[1]), fmaxf(s_redM[2], s_redM[3]));
    const float e0 = expf(v[0] - rowmax), e1 = expf(v[1] - rowmax);
    float s = e0 + e1;
#pragma unroll
    for (int o = 32; o; o >>= 1) s += __shfl_down(s, o);
    if (lane == 0) s_redS[wv] = s;
    __syncthreads();
    const float scale = 0.9f / (s_redS[0] + s_redS[1] + s_redS[2] + s_redS[3]);
    const float w0 = e0 * scale + ((t == i) ? 0.1f : 0.0f);
    const float w1 = e1 * scale + ((t + 256 == i) ? 0.1f : 0.0f);
    ew[i * NC + t] = f2bf(w0);
    ew[i * NC + t + 256] = f2bf(w1);
}

// ---------------------------------------------------------------------------
// K2: GEMM with in-kernel transpose, on the R2-PROVEN sync schedule:
//   double-buffered smA/smT, ONE __syncthreads per K-step, STAGE(next) issued
//   immediately after the barrier, compute reads the other buffer; the next
//   barrier's vmcnt(0)+lgkmcnt(0) drain completes the stage (R2 passed
//   post-timing replay with this exact contract).
// x_t[b,i,d] = sum_j ew[i,j]*x[b,j,d], written bf16 to ws.
// 128x128 tile, BK=32, 16 K-steps, 4 waves (2x2 of 64x64 sub-tiles).
// A (ew): global_load_lds into linear [128][32] bf16 (R1/R2-proven).
// B (x): f32 reg-prefetch (2 steps ahead) -> cvt bf16 -> smT[32 j][ST d]
//        row-major; fragments via 8x ds_read_u16 at row-stride ST.
// Grid 2048 = 64 b x (4 i x 8 d), XCD-swizzled: 32 blocks of batch b per XCD
// -> x[b] (2 MB f32) L2-resident, HBM reads x ~once.
// ---------------------------------------------------------------------------
__global__ __launch_bounds__(256) void gemm_tr2(
    const unsigned short* __restrict__ ew, const float* __restrict__ x,
    unsigned short* __restrict__ xt) {
    __shared__ __align__(16) unsigned short smA[2][128 * 32];  // 2 x 8 KB
    __shared__ __align__(16) unsigned short smT[2][32 * ST];   // 2 x 8.25 KB
    const int t = threadIdx.x;
    const int lane = t & 63, w = t >> 6;
    const int wr = w >> 1, wc = w & 1;

    const int bid = blockIdx.x;
    const int slot = bid & 7, idx = bid >> 3;  // slot = XCD
    const int bq = idx >> 5, inner = idx & 31;
    const int b = slot + bq * 8;               // b % 8 == XCD
    const int i_t = inner >> 3, d_t = inner & 7;
    const int i0 = i_t * 128, d0 = d_t * 128;

    // A staging addresses (R1/R2-proven pattern)
    const unsigned short* gA = ew + (size_t)(i0 + (t >> 2)) * NC + (t & 3) * 8;

    // B loading: thread t -> j-row tj = t>>3 (0..31), d-chunk tds = t&7 (x16)
    const int tj = t >> 3, tds = t & 7;
    const float* gB = x + ((size_t)(b * NC) + tj) * FD + d0 + tds * 16;

    const int lr = lane & 15, kidx = lane >> 4;

    f32x4 acc[4][4];
#pragma unroll
    for (int mi = 0; mi < 4; ++mi)
#pragma unroll
        for (int ni = 0; ni < 4; ++ni) acc[mi][ni] = (f32x4){0.f, 0.f, 0.f, 0.f};

    float4 rb0, rb1, rb2, rb3;

    // ---- helpers (inlined lambdas; all indices compile-time-friendly) ----
    auto LOAD_B = [&](int s) {  // prefetch tile s rows into regs
        const float4* p = reinterpret_cast<const float4*>(gB + (size_t)s * 32 * FD);
        rb0 = p[0]; rb1 = p[1]; rb2 = p[2]; rb3 = p[3];
    };
    auto STAGE_A = [&](int s, int pb) {  // gload_lds A k-tile s into smA[pb]
        const int k0 = s * 32;
        gload_lds16(gA + k0, &smA[pb][t * 8]);
        gload_lds16(gA + (size_t)64 * NC + k0, &smA[pb][64 * 32 + t * 8]);
    };
    auto STAGE_B = [&](int pb) {  // cvt current rb regs -> smT[pb] (8B stores)
        float v[16] = {rb0.x, rb0.y, rb0.z, rb0.w, rb1.x, rb1.y, rb1.z, rb1.w,
                       rb2.x, rb2.y, rb2.z, rb2.w, rb3.x, rb3.y, rb3.z, rb3.w};
        ushort4 a, c;
        a.x = f2bf(v[0]);  a.y = f2bf(v[1]);  a.z = f2bf(v[2]);  a.w = f2bf(v[3]);
        c.x = f2bf(v[4]);  c.y = f2bf(v[5]);  c.z = f2bf(v[6]);  c.w = f2bf(v[7]);
        ushort4 e, g;
        e.x = f2bf(v[8]);  e.y = f2bf(v[9]);  e.z = f2bf(v[10]); e.w = f2bf(v[11]);
        g.x = f2bf(v[12]); g.y = f2bf(v[13]); g.z = f2bf(v[14]); g.w = f2bf(v[15]);
        unsigned short* sT = &smT[pb][tj * ST + tds * 16];  // byte: 264*tj+32*tds (8B-aligned)
        *reinterpret_cast<ushort4*>(sT + 0) = a;
        *reinterpret_cast<ushort4*>(sT + 4) = c;
        *reinterpret_cast<ushort4*>(sT + 8) = e;
        *reinterpret_cast<ushort4*>(sT + 12) = g;
    };

    // ---- prologue: stage tile 0 into buf 0; prefetch tile 1 ----
    LOAD_B(0);
    STAGE_A(0, 0);
    STAGE_B(0);
    LOAD_B(1);

    int p = 0;
    for (int s = 0; s < 16; ++s) {
        __syncthreads();  // drains vmcnt (stage-A gloads, rb prefetch) + lgkm (smT writes, prev reads)
        if (s < 15) {
            STAGE_A(s + 1, p ^ 1);
            STAGE_B(p ^ 1);   // consumes rb = tile s+1
        }
        if (s < 14) LOAD_B(s + 2);

        // A fragments (proven: linear [row][32k], bf16x8 at kidx*8)
        const bf16x8* A8 = reinterpret_cast<const bf16x8*>(smA[p]);
        bf16x8 aF[4];
#pragma unroll
        for (int mi = 0; mi < 4; ++mi)
            aF[mi] = A8[(wr * 64 + mi * 16 + lr) * 4 + kidx];
        // B fragments: elem e of frag ni = smT[p][(kidx*8+e)*ST + n]
        bf16x8 bF[4];
#pragma unroll
        for (int ni = 0; ni < 4; ++ni) {
            const int nb = wc * 64 + ni * 16 + lr;
            const int rbase = kidx * 8;
            unsigned int q[4];
#pragma unroll
            for (int qq = 0; qq < 4; ++qq) {
                unsigned int lo = smT[p][(rbase + 2 * qq) * ST + nb];
                unsigned int hi = smT[p][(rbase + 2 * qq + 1) * ST + nb];
                q[qq] = lo | (hi << 16);
            }
            bF[ni] = __builtin_bit_cast(bf16x8, (u32x4){q[0], q[1], q[2], q[3]});
        }
#pragma unroll
        for (int mi = 0; mi < 4; ++mi)
#pragma unroll
            for (int ni = 0; ni < 4; ++ni)
                acc[mi][ni] = __builtin_amdgcn_mfma_f32_16x16x32_bf16(
                    aF[mi], bF[ni], acc[mi][ni], 0, 0, 0);
        p ^= 1;
    }

    // epilogue: x_t bf16 -> ws. C/D layout: col = lane&15, row = (lane>>4)*4+r
    const int r0 = (lane >> 4) * 4;
#pragma unroll
    for (int mi = 0; mi < 4; ++mi)
#pragma unroll
        for (int ni = 0; ni < 4; ++ni)
#pragma unroll
            for (int r = 0; r < 4; ++r) {
                const size_t R = (size_t)(b * NC + i0 + wr * 64 + mi * 16 + r0 + r);
                xt[R * FD + d0 + wc * 64 + ni * 16 + lr] = f2bf(acc[mi][ni][r]);
            }
}

// ---------------------------------------------------------------------------
// K3: gate. One block per (b,i) row: g = sigmoid(dot(x, x_t)/32);
// out = x*(1-g) + x_t*g. x_t read as bf16 from ws. (R2-proven math)
// ---------------------------------------------------------------------------
__global__ __launch_bounds__(256) void gate_out(
    const float* __restrict__ x, const unsigned short* __restrict__ xt,
    float* __restrict__ out) {
    __shared__ float s[4];
    const int row = blockIdx.x;
    const int t = threadIdx.x;
    const size_t base = (size_t)row * FD + t * 4;
    const float4 xv = *reinterpret_cast<const float4*>(x + base);
    const ushort4 uv = *reinterpret_cast<const ushort4*>(xt + base);
    const float t0 = bf2f(uv.x), t1 = bf2f(uv.y), t2 = bf2f(uv.z), t3 = bf2f(uv.w);
    float p = xv.x * t0 + xv.y * t1 + xv.z * t2 + xv.w * t3;
#pragma unroll
    for (int o = 32; o; o >>= 1) p += __shfl_down(p, o);
    if ((t & 63) == 0) s[t >> 6] = p;
    __syncthreads();
    const float dot = s[0] + s[1] + s[2] + s[3];
    const float g = 1.0f / (1.0f + expf(-dot * 0.03125f));
    float4 ov;
    ov.x = xv.x * (1.0f - g) + t0 * g;
    ov.y = xv.y * (1.0f - g) + t1 * g;
    ov.z = xv.z * (1.0f - g) + t2 * g;
    ov.w = xv.w * (1.0f - g) + t3 * g;
    *reinterpret_cast<float4*>(out + base) = ov;
}

extern "C" void kernel_launch(void* const* d_in, const int* in_sizes, int n_in,
                              void* d_out, int out_size, void* d_ws, size_t ws_size,
                              hipStream_t stream) {
    const float* x = (const float*)d_in[0];
    const float* co = (const float*)d_in[1];
    const float* counts = (const float*)d_in[2];
    const float* emb = (const float*)d_in[3];
    float* out = (float*)d_out;

    unsigned short* ew = (unsigned short*)d_ws;                        // 512 KB
    unsigned short* xt = (unsigned short*)((char*)d_ws + (1u << 20));  // 64 MiB

    build_ew<<<NC, 256, 0, stream>>>(co, counts, emb, ew);
    gemm_tr2<<<2048, 256, 0, stream>>>(ew, x, xt);
    gate_out<<<NB * NC, 256, 0, stream>>>(x, xt, out);
}

// Round 6
// 121.799 us; speedup vs baseline: 1.4732x; 1.0834x over previous
//
#include <hip/hip_runtime.h>
#include <hip/hip_bf16.h>
#include <stdint.h>

// Problem constants
#define NC 512     // NUM_CLASSES
#define FD 1024    // FEAT_DIM
#define NB 64      // BATCH
#define SMOOTH_ 0.01f
#define STQ 40     // Bt row stride in u16 (32 data + 8 pad): 80 B rows, 16B-aligned

typedef __bf16 bf16x8 __attribute__((ext_vector_type(8)));
typedef float f32x4 __attribute__((ext_vector_type(4)));

__device__ __forceinline__ unsigned short f2bf(float f) {
    __hip_bfloat16 h = __float2bfloat16(f);
    return __builtin_bit_cast(unsigned short, h);
}
__device__ __forceinline__ float bf2f(unsigned short u) {
    unsigned int v = (unsigned int)u << 16;
    return __builtin_bit_cast(float, v);
}

__device__ __forceinline__ void gload_lds16(const void* g, void* l) {
    __builtin_amdgcn_global_load_lds(
        (const __attribute__((address_space(1))) void*)(uintptr_t)g,
        (__attribute__((address_space(3))) void*)(uint32_t)(uintptr_t)l,
        16, 0, 0);
}

// ---------------------------------------------------------------------------
// K1: build edge weights ew[512][512], store as bf16 bits. (unchanged, verified)
// ---------------------------------------------------------------------------
__global__ __launch_bounds__(256) void build_ew(
    const float* __restrict__ co, const float* __restrict__ counts,
    const float* __restrict__ emb, unsigned short* __restrict__ ew) {
    __shared__ float s_counts[NC];
    __shared__ float s_nemb[NC * 4];
    __shared__ float s_redA[4], s_redM[4], s_redS[4];
    const int i = blockIdx.x;
    const int t = threadIdx.x;
    const int lane = t & 63, wv = t >> 6;

    float c0 = counts[t], c1 = counts[t + 256];
    s_counts[t] = c0;
    s_counts[t + 256] = c1;
    for (int r = t; r < NC; r += 256) {
        float e0 = emb[r * 4 + 0], e1 = emb[r * 4 + 1];
        float e2 = emb[r * 4 + 2], e3 = emb[r * 4 + 3];
        float inv = 1.0f / sqrtf(e0 * e0 + e1 * e1 + e2 * e2 + e3 * e3);
        s_nemb[r * 4 + 0] = e0 * inv;
        s_nemb[r * 4 + 1] = e1 * inv;
        s_nemb[r * 4 + 2] = e2 * inv;
        s_nemb[r * 4 + 3] = e3 * inv;
    }
    float p = c0 + c1;
#pragma unroll
    for (int o = 32; o; o >>= 1) p += __shfl_down(p, o);
    if (lane == 0) s_redA[wv] = p;
    __syncthreads();
    const float avg = (s_redA[0] + s_redA[1] + s_redA[2] + s_redA[3]) * (1.0f / 512.0f);

    const float ci = s_counts[i];
    const float ni0 = s_nemb[i * 4 + 0], ni1 = s_nemb[i * 4 + 1];
    const float ni2 = s_nemb[i * 4 + 2], ni3 = s_nemb[i * 4 + 3];

    float v[2];
#pragma unroll
    for (int u = 0; u < 2; ++u) {
        const int j = t + u * 256;
        const float c = co[i * NC + j];
        const float cj = s_counts[j];
        const float nco = (c + SMOOTH_) / sqrtf((ci + SMOOTH_) * (cj + SMOOTH_));
        const float sim = ni0 * s_nemb[j * 4 + 0] + ni1 * s_nemb[j * 4 + 1] +
                          ni2 * s_nemb[j * 4 + 2] + ni3 * s_nemb[j * 4 + 3];
        const float aff = sim / (1.0f + expf(-(sim - 0.5f) * 10.0f));
        const float mn = fminf(ci, cj), mx = fmaxf(ci, cj);
        const float bal = (mn > SMOOTH_ && mx > SMOOTH_)
                              ? log1pf(mx / avg) * (mn / mx)
                              : SMOOTH_;
        const float conf = 2.0f / (1.0f + expf(-c * 0.2f)) - 1.0f;
        const float e = (j == i) ? 0.0f : nco * aff * bal * conf;
        v[u] = e * 5.0f;
    }
    float m = fmaxf(v[0], v[1]);
#pragma unroll
    for (int o = 32; o; o >>= 1) m = fmaxf(m, __shfl_down(m, o));
    if (lane == 0) s_redM[wv] = m;
    __syncthreads();
    const float rowmax = fmaxf(fmaxf(s_redM[0], s_redM[1]), fmaxf(s_redM[2], s_redM[3]));
    const float e0 = expf(v[0] - rowmax), e1 = expf(v[1] - rowmax);
    float s = e0 + e1;
#pragma unroll
    for (int o = 32; o; o >>= 1) s += __shfl_down(s, o);
    if (lane == 0) s_redS[wv] = s;
    __syncthreads();
    const float scale = 0.9f / (s_redS[0] + s_redS[1] + s_redS[2] + s_redS[3]);
    const float w0 = e0 * scale + ((t == i) ? 0.1f : 0.0f);
    const float w1 = e1 * scale + ((t + 256 == i) ? 0.1f : 0.0f);
    ew[i * NC + t] = f2bf(w0);
    ew[i * NC + t + 256] = f2bf(w1);
}

// ---------------------------------------------------------------------------
// K2: GEMM with in-kernel transpose, transposed-on-WRITE LDS B-tile.
// x_t[b,i,d] = sum_j ew[i,j]*x[b,j,d], written bf16 to ws.
// Sync skeleton identical to R5 (proven replay-safe): double-buffered
// smA/smT, ONE __syncthreads per K-step, STAGE(next) after the barrier,
// compute reads the other buffer.
// B path (new): Bt[128 d][STQ=40 j-stride] stores the tile TRANSPOSED.
//   Write: thread (jp=t>>4, m=t&15) owns j={2jp,2jp+1}, d={m+16e}e=0..7;
//          packs 2 bf16 (adjacent j) per u32 -> 8x ds_write_b32.
//          banks = (20m + jp) mod 32 -> all 32 banks, 2 lanes each = free.
//   Read:  bF[ni] = one ds_read_b128 at Bt[nb][kidx*8], nb=wc*64+ni*16+lr;
//          uniform 8 lanes per 4-bank window = free.
// A path, MFMA, epilogue: R1/R5-proven.
// Grid 2048 = 64 b x (4 i x 8 d), XCD-swizzled (32 blocks of b per XCD).
// ---------------------------------------------------------------------------
__global__ __launch_bounds__(256) void gemm_tr2(
    const unsigned short* __restrict__ ew, const float* __restrict__ x,
    unsigned short* __restrict__ xt) {
    __shared__ __align__(16) unsigned short smA[2][128 * 32];   // 2 x 8 KB
    __shared__ __align__(16) unsigned short smT[2][128 * STQ];  // 2 x 10 KB
    const int t = threadIdx.x;
    const int lane = t & 63, w = t >> 6;
    const int wr = w >> 1, wc = w & 1;

    const int bid = blockIdx.x;
    const int slot = bid & 7, idx = bid >> 3;  // slot = XCD
    const int bq = idx >> 5, inner = idx & 31;
    const int b = slot + bq * 8;               // b % 8 == XCD
    const int i_t = inner >> 3, d_t = inner & 7;
    const int i0 = i_t * 128, d0 = d_t * 128;

    // A staging addresses (R1/R5-proven pattern)
    const unsigned short* gA = ew + (size_t)(i0 + (t >> 2)) * NC + (t & 3) * 8;

    // B loading map: jp = t>>4 (j-pair 0..15), m = t&15 (d residue)
    const int jp = t >> 4, m = t & 15;
    const float* gB0 = x + ((size_t)(b * NC) + 2 * jp) * FD + d0 + m;  // j even
    const float* gB1 = gB0 + FD;                                       // j odd

    const int lr = lane & 15, kidx = lane >> 4;

    f32x4 acc[4][4];
#pragma unroll
    for (int mi = 0; mi < 4; ++mi)
#pragma unroll
        for (int ni = 0; ni < 4; ++ni) acc[mi][ni] = (f32x4){0.f, 0.f, 0.f, 0.f};

    float r0[8], r1[8];  // prefetched x values: r0 = j even, r1 = j odd; d = m+16e

    auto LOAD_B = [&](int s) {
        const size_t off = (size_t)s * 32 * FD;
#pragma unroll
        for (int e = 0; e < 8; ++e) {
            r0[e] = gB0[off + 16 * e];
            r1[e] = gB1[off + 16 * e];
        }
    };
    auto STAGE_A = [&](int s, int pb) {
        const int k0 = s * 32;
        gload_lds16(gA + k0, &smA[pb][t * 8]);
        gload_lds16(gA + (size_t)64 * NC + k0, &smA[pb][64 * 32 + t * 8]);
    };
    auto STAGE_B = [&](int pb) {  // transposed write: Bt[d][j], 8x b32
        unsigned int* bt32 = reinterpret_cast<unsigned int*>(smT[pb]);
#pragma unroll
        for (int e = 0; e < 8; ++e) {
            const int d = m + 16 * e;
            const unsigned int val =
                (unsigned int)f2bf(r0[e]) | ((unsigned int)f2bf(r1[e]) << 16);
            bt32[d * (STQ / 2) + jp] = val;
        }
    };

    // ---- prologue: stage tile 0 into buf 0; prefetch tile 1 ----
    LOAD_B(0);
    STAGE_A(0, 0);
    STAGE_B(0);
    LOAD_B(1);

    int p = 0;
    for (int s = 0; s < 16; ++s) {
        __syncthreads();  // drains vmcnt (A gloads, B prefetch) + lgkm (Bt writes, prev reads)
        if (s < 15) {
            STAGE_A(s + 1, p ^ 1);
            STAGE_B(p ^ 1);  // consumes r0/r1 = tile s+1
        }
        if (s < 14) LOAD_B(s + 2);

        // A fragments (proven: linear [row][32k], bf16x8 at kidx*8)
        const bf16x8* A8 = reinterpret_cast<const bf16x8*>(smA[p]);
        bf16x8 aF[4];
#pragma unroll
        for (int mi = 0; mi < 4; ++mi)
            aF[mi] = A8[(wr * 64 + mi * 16 + lr) * 4 + kidx];
        // B fragments: one b128 each from transposed tile
        bf16x8 bF[4];
#pragma unroll
        for (int ni = 0; ni < 4; ++ni) {
            const int nb = wc * 64 + ni * 16 + lr;
            bF[ni] = *reinterpret_cast<const bf16x8*>(&smT[p][nb * STQ + kidx * 8]);
        }
#pragma unroll
        for (int mi = 0; mi < 4; ++mi)
#pragma unroll
            for (int ni = 0; ni < 4; ++ni)
                acc[mi][ni] = __builtin_amdgcn_mfma_f32_16x16x32_bf16(
                    aF[mi], bF[ni], acc[mi][ni], 0, 0, 0);
        p ^= 1;
    }

    // epilogue: x_t bf16 -> ws. C/D layout: col = lane&15, row = (lane>>4)*4+r
    const int r0e = (lane >> 4) * 4;
#pragma unroll
    for (int mi = 0; mi < 4; ++mi)
#pragma unroll
        for (int ni = 0; ni < 4; ++ni)
#pragma unroll
            for (int r = 0; r < 4; ++r) {
                const size_t R = (size_t)(b * NC + i0 + wr * 64 + mi * 16 + r0e + r);
                xt[R * FD + d0 + wc * 64 + ni * 16 + lr] = f2bf(acc[mi][ni][r]);
            }
}

// ---------------------------------------------------------------------------
// K3: gate. One block per (b,i) row: g = sigmoid(dot(x, x_t)/32);
// out = x*(1-g) + x_t*g. x_t read as bf16 from ws. (proven)
// ---------------------------------------------------------------------------
__global__ __launch_bounds__(256) void gate_out(
    const float* __restrict__ x, const unsigned short* __restrict__ xt,
    float* __restrict__ out) {
    __shared__ float s[4];
    const int row = blockIdx.x;
    const int t = threadIdx.x;
    const size_t base = (size_t)row * FD + t * 4;
    const float4 xv = *reinterpret_cast<const float4*>(x + base);
    const ushort4 uv = *reinterpret_cast<const ushort4*>(xt + base);
    const float t0 = bf2f(uv.x), t1 = bf2f(uv.y), t2 = bf2f(uv.z), t3 = bf2f(uv.w);
    float p = xv.x * t0 + xv.y * t1 + xv.z * t2 + xv.w * t3;
#pragma unroll
    for (int o = 32; o; o >>= 1) p += __shfl_down(p, o);
    if ((t & 63) == 0) s[t >> 6] = p;
    __syncthreads();
    const float dot = s[0] + s[1] + s[2] + s[3];
    const float g = 1.0f / (1.0f + expf(-dot * 0.03125f));
    float4 ov;
    ov.x = xv.x * (1.0f - g) + t0 * g;
    ov.y = xv.y * (1.0f - g) + t1 * g;
    ov.z = xv.z * (1.0f - g) + t2 * g;
    ov.w = xv.w * (1.0f - g) + t3 * g;
    *reinterpret_cast<float4*>(out + base) = ov;
}

extern "C" void kernel_launch(void* const* d_in, const int* in_sizes, int n_in,
                              void* d_out, int out_size, void* d_ws, size_t ws_size,
                              hipStream_t stream) {
    const float* x = (const float*)d_in[0];
    const float* co = (const float*)d_in[1];
    const float* counts = (const float*)d_in[2];
    const float* emb = (const float*)d_in[3];
    float* out = (float*)d_out;

    unsigned short* ew = (unsigned short*)d_ws;                        // 512 KB
    unsigned short* xt = (unsigned short*)((char*)d_ws + (1u << 20));  // 64 MiB

    build_ew<<<NC, 256, 0, stream>>>(co, counts, emb, ew);
    gemm_tr2<<<2048, 256, 0, stream>>>(ew, x, xt);
    gate_out<<<NB * NC, 256, 0, stream>>>(x, xt, out);
}